// Round 15
// baseline (51.865 us; speedup 1.0000x reference)
//
#include <hip/hip_runtime.h>

// Denoiser MLP (2->16, 5x 16->16, 16->2), fp32 in/out, via v_mfma_f32_32x32x16_f16.
// R15: non-persistent launch to restore residency.
// Chain arithmetic: 14-stage serial MFMA->cvt chain ~100 cyc/stage = 1400
// cyc/body; 64 bodies/SIMD / 2.6 resident waves (persistent rounds' measured
// occupancy) = 34us == the R6-R14 plateau. R3 (non-persistent, 16384 blocks)
// is the only round that measured high occupancy (61.7%). Persistent 2048-
// block dispatch starves residency; per-block relaunch refills wave slots as
// blocks retire. Body = R14's (proven, absmax 7.8e-3); weight prep once per
// block (~40 instr, L2-hot loads) is the price of admission.
//
// Mapping (verified R6-R14):
//   A (32x16) = [W; W], B (16x32) = 32 points' features (transposed)
//   A frag: lane l holds A[i=l&31][k=8*(l>>5)+j]
//   B frag: lane l holds B[k=8*(l>>5)+j][n=l&31]
//   D frag: lane l holds D[i=(reg&3)+8*(reg>>2)+4*(l>>5)][n=l&31]
// D regs 0-7 at hi=l>>5 = rows {0-3,8-11}/{4-7,12-15}; next-layer weights
// column-permuted [0-3,8-11 | 4-7,12-15] -> layers chain in register order.
// Input trick: bin = pack4(cvtpk(x,y),0,0,0); wi0 (W at k0,1) computes hi=0
// lanes' points (stream0 = pts base+0..31), wi1 (W at k8,9) hi=1 lanes'
// (stream1 = pts base+32..63).

typedef _Float16 h8 __attribute__((ext_vector_type(8)));
typedef float f16v __attribute__((ext_vector_type(16)));
typedef float f4 __attribute__((ext_vector_type(4)));
typedef float f2 __attribute__((ext_vector_type(2)));
typedef unsigned int u32;
typedef u32 u4v __attribute__((ext_vector_type(4)));

static __device__ __forceinline__ f16v mfma32(h8 a, h8 b, f16v c) {
    return __builtin_amdgcn_mfma_f32_32x32x16_f16(a, b, c, 0, 0, 0);
}

static __device__ __forceinline__ u32 cvtpk(float a, float b) {
    return __builtin_bit_cast(u32, __builtin_amdgcn_cvt_pkrtz(a, b));
}

static __device__ __forceinline__ h8 pack4(u32 a, u32 b, u32 c, u32 d) {
    u4v p = {a, b, c, d};
    return __builtin_bit_cast(h8, p);
}

// quad-permuted weight fragment: j0-3 = cols 4*hi.., j4-7 = cols 8+4*hi..
static __device__ __forceinline__ h8 wfrag(const float* row, int hi) {
    const f4* r4 = (const f4*)row;
    f4 q0 = r4[hi], q1 = r4[hi + 2];
    return pack4(cvtpk(q0.x, q0.y), cvtpk(q0.z, q0.w),
                 cvtpk(q1.x, q1.y), cvtpk(q1.z, q1.w));
}

// relu + cvt of D regs 0-7 -> next layer's B fragment (order-preserving)
static __device__ __forceinline__ h8 cvt_relu8(f16v a) {
    h8 hb = pack4(cvtpk(a[0], a[1]), cvtpk(a[2], a[3]),
                  cvtpk(a[4], a[5]), cvtpk(a[6], a[7]));
    const h8 z = {};
    return __builtin_elementwise_max(hb, z);
}

__global__ __launch_bounds__(256, 4) void denoiser_mfma32(
    const f2* __restrict__ x,        // [N] points (x0,x1)
    const float* __restrict__ w_in,  // [16][2]
    const float* __restrict__ w_mid, // [5][16][16]
    const float* __restrict__ w_out, // [2][16]
    f2* __restrict__ out,            // [N] (o0,o1)
    int n)
{
    const int lane = threadIdx.x & 63;
    const int m    = lane & 15;   // weight row (rows duplicated mod 16)
    const int hi   = lane >> 5;   // half-wave / k-group
    const int wave = threadIdx.x >> 6;

    const h8 hz = {};

    // ---- weight fragments (once per block; loads are L2-hot) ----
    u32 wxy = cvtpk(w_in[2 * m], w_in[2 * m + 1]);
    h8 wi0 = hi == 0 ? pack4(wxy, 0u, 0u, 0u) : hz;   // stream0: pts 0..31
    h8 wi1 = hi == 1 ? pack4(wxy, 0u, 0u, 0u) : hz;   // stream1: pts 32..63

    h8 wm0 = wfrag(w_mid + 0 * 256 + m * 16, hi);
    h8 wm1 = wfrag(w_mid + 1 * 256 + m * 16, hi);
    h8 wm2 = wfrag(w_mid + 2 * 256 + m * 16, hi);
    h8 wm3 = wfrag(w_mid + 3 * 256 + m * 16, hi);
    h8 wm4 = wfrag(w_mid + 4 * 256 + m * 16, hi);

    h8 wo = m < 2 ? wfrag(w_out + m * 16, hi) : hz;

    // one-time pin: zero C-operand stays resident, un-rematerializable
    f16v z16 = {};
    asm("" : "+v"(z16));

    const int base = blockIdx.x * 256 + wave * 64;   // this wave's 64 points

    f2 xy;
    {
        int pi = base + lane;
        xy = x[pi < n ? pi : n - 1];
    }
    h8 bin = pack4(cvtpk(xy.x, xy.y), 0u, 0u, 0u);

    // one 32-pt stream: input MFMA, 5 mid layers, output MFMA, store.
    auto stream = [&](h8 wi, int sbase) {
        f16v a = mfma32(wi, bin, z16);
        h8 b = cvt_relu8(a);
        a = mfma32(wm0, b, z16);  b = cvt_relu8(a);
        a = mfma32(wm1, b, z16);  b = cvt_relu8(a);
        a = mfma32(wm2, b, z16);  b = cvt_relu8(a);
        a = mfma32(wm3, b, z16);  b = cvt_relu8(a);
        a = mfma32(wm4, b, z16);  b = cvt_relu8(a);
        a = mfma32(wo, b, z16);

        if (lane < 32) {
            int p0 = sbase + lane;
            if (p0 < n) out[p0] = (f2){a[0], a[1]};
        }
    };

    stream(wi0, base);        // pts base+ 0..31 (hi=0 lanes' data)
    stream(wi1, base + 32);   // pts base+32..63 (hi=1 lanes' data)
}

extern "C" void kernel_launch(void* const* d_in, const int* in_sizes, int n_in,
                              void* d_out, int out_size, void* d_ws, size_t ws_size,
                              hipStream_t stream) {
    const float* x     = (const float*)d_in[0];
    const float* w_in  = (const float*)d_in[1];
    const float* w_mid = (const float*)d_in[2];
    const float* w_out = (const float*)d_in[3];

    int n = in_sizes[0] / 2;          // number of points
    int blocks = (n + 255) / 256;     // one 256-pt chunk per block

    denoiser_mfma32<<<blocks, 256, 0, stream>>>(
        (const f2*)x, w_in, w_mid, w_out, (f2*)d_out, n);
}

// Round 16
// 44.589 us; speedup vs baseline: 1.1632x; 1.1632x over previous
//
#include <hip/hip_runtime.h>

// Denoiser MLP (2->16, 5x 16->16, 16->2), fp32 in/out, via v_mfma_f32_32x32x16_f16.
// R16: eliminate suspected f16-vector-max scalarization -- safely.
// Invariant across R6-R15: VALU-busy ~21us == ~394 VALU instr/body vs ~120
// in source. Suspect: __builtin_elementwise_max on h8 scalarizes (~24 instr
// vs 4 v_pk_max_f16) = +240/body. R12's asm fix broke numerics (VOP3P
// op_sel_hi); this round does ReLU in f32 SCALAR form instead:
// cvtpk(fmaxf(a,0), fmaxf(b,0)) -- fmaxf(x,0.f) is a single v_max_f32 with
// inline-constant 0, nothing for clang to scalarize. 12 instr/fragment by
// construction. max-then-cvt == cvt-then-max for RTZ. Structure = R11
// (best passing: persistent, depth-2 prefetch, lb(256,4)).
//
// Mapping (verified R6-R15, absmax 7.8e-3):
//   A (32x16) = [W; W], B (16x32) = 32 points' features (transposed)
//   A frag: lane l holds A[i=l&31][k=8*(l>>5)+j]
//   B frag: lane l holds B[k=8*(l>>5)+j][n=l&31]
//   D frag: lane l holds D[i=(reg&3)+8*(reg>>2)+4*(l>>5)][n=l&31]
// D regs 0-7 at hi=l>>5 = rows {0-3,8-11}/{4-7,12-15}; next-layer weights
// column-permuted [0-3,8-11 | 4-7,12-15] -> layers chain in register order.
// Input trick: bin = pack4(cvtpk(x,y),0,0,0); wi0 (W at k0,1) computes hi=0
// lanes' points (stream0 = pts base+0..31), wi1 (W at k8,9) hi=1 lanes'
// (stream1 = pts base+32..63).

typedef _Float16 h8 __attribute__((ext_vector_type(8)));
typedef float f16v __attribute__((ext_vector_type(16)));
typedef float f4 __attribute__((ext_vector_type(4)));
typedef float f2 __attribute__((ext_vector_type(2)));
typedef unsigned int u32;
typedef u32 u4v __attribute__((ext_vector_type(4)));

static __device__ __forceinline__ f16v mfma32(h8 a, h8 b, f16v c) {
    return __builtin_amdgcn_mfma_f32_32x32x16_f16(a, b, c, 0, 0, 0);
}

static __device__ __forceinline__ u32 cvtpk(float a, float b) {
    return __builtin_bit_cast(u32, __builtin_amdgcn_cvt_pkrtz(a, b));
}

static __device__ __forceinline__ h8 pack4(u32 a, u32 b, u32 c, u32 d) {
    u4v p = {a, b, c, d};
    return __builtin_bit_cast(h8, p);
}

// quad-permuted weight fragment: j0-3 = cols 4*hi.., j4-7 = cols 8+4*hi..
static __device__ __forceinline__ h8 wfrag(const float* row, int hi) {
    const f4* r4 = (const f4*)row;
    f4 q0 = r4[hi], q1 = r4[hi + 2];
    return pack4(cvtpk(q0.x, q0.y), cvtpk(q0.z, q0.w),
                 cvtpk(q1.x, q1.y), cvtpk(q1.z, q1.w));
}

// relu (f32 scalar, v_max_f32 w/ inline 0) + cvt -> next layer's B fragment.
// Exactly 8 v_max_f32 + 4 v_cvt_pkrtz by construction.
static __device__ __forceinline__ h8 cvt_relu8(f16v a) {
    u32 c0 = cvtpk(__builtin_fmaxf(a[0], 0.f), __builtin_fmaxf(a[1], 0.f));
    u32 c1 = cvtpk(__builtin_fmaxf(a[2], 0.f), __builtin_fmaxf(a[3], 0.f));
    u32 c2 = cvtpk(__builtin_fmaxf(a[4], 0.f), __builtin_fmaxf(a[5], 0.f));
    u32 c3 = cvtpk(__builtin_fmaxf(a[6], 0.f), __builtin_fmaxf(a[7], 0.f));
    return pack4(c0, c1, c2, c3);
}

__global__ __launch_bounds__(256, 4) void denoiser_mfma32(
    const f2* __restrict__ x,        // [N] points (x0,x1)
    const float* __restrict__ w_in,  // [16][2]
    const float* __restrict__ w_mid, // [5][16][16]
    const float* __restrict__ w_out, // [2][16]
    f2* __restrict__ out,            // [N] (o0,o1)
    int n)
{
    const int lane = threadIdx.x & 63;
    const int m    = lane & 15;   // weight row (rows duplicated mod 16)
    const int hi   = lane >> 5;   // half-wave / k-group
    const int wave = threadIdx.x >> 6;

    const h8 hz = {};

    // ---- one-time weight fragments ----
    u32 wxy = cvtpk(w_in[2 * m], w_in[2 * m + 1]);
    h8 wi0 = hi == 0 ? pack4(wxy, 0u, 0u, 0u) : hz;   // stream0: pts 0..31
    h8 wi1 = hi == 1 ? pack4(wxy, 0u, 0u, 0u) : hz;   // stream1: pts 32..63

    h8 wm0 = wfrag(w_mid + 0 * 256 + m * 16, hi);
    h8 wm1 = wfrag(w_mid + 1 * 256 + m * 16, hi);
    h8 wm2 = wfrag(w_mid + 2 * 256 + m * 16, hi);
    h8 wm3 = wfrag(w_mid + 3 * 256 + m * 16, hi);
    h8 wm4 = wfrag(w_mid + 4 * 256 + m * 16, hi);

    h8 wo = m < 2 ? wfrag(w_out + m * 16, hi) : hz;

    // one-time pin: zero C-operand stays resident, un-rematerializable
    f16v z16 = {};
    asm("" : "+v"(z16));

    const int nchunks = (n + 255) >> 8;     // 256-pt block chunks
    const int stride  = gridDim.x;
    const int nm1     = n - 1;

    auto loadx = [&](int c) -> f2 {
        int pi = c * 256 + wave * 64 + lane;
        return x[pi < n ? pi : nm1];
    };

    auto body = [&](int c, f2 xy) {
        const int base = c * 256 + wave * 64;
        h8 bin = pack4(cvtpk(xy.x, xy.y), 0u, 0u, 0u);
        f16v a0 = mfma32(wi0, bin, z16);
        f16v a1 = mfma32(wi1, bin, z16);
        h8 b0 = cvt_relu8(a0);
        h8 b1 = cvt_relu8(a1);

        a0 = mfma32(wm0, b0, z16);  a1 = mfma32(wm0, b1, z16);
        b0 = cvt_relu8(a0);         b1 = cvt_relu8(a1);
        a0 = mfma32(wm1, b0, z16);  a1 = mfma32(wm1, b1, z16);
        b0 = cvt_relu8(a0);         b1 = cvt_relu8(a1);
        a0 = mfma32(wm2, b0, z16);  a1 = mfma32(wm2, b1, z16);
        b0 = cvt_relu8(a0);         b1 = cvt_relu8(a1);
        a0 = mfma32(wm3, b0, z16);  a1 = mfma32(wm3, b1, z16);
        b0 = cvt_relu8(a0);         b1 = cvt_relu8(a1);
        a0 = mfma32(wm4, b0, z16);  a1 = mfma32(wm4, b1, z16);
        b0 = cvt_relu8(a0);         b1 = cvt_relu8(a1);

        a0 = mfma32(wo, b0, z16);
        a1 = mfma32(wo, b1, z16);

        if (lane < 32) {
            int p0 = base + lane;
            if (base + 64 <= n) {
                out[p0]      = (f2){a0[0], a0[1]};
                out[p0 + 32] = (f2){a1[0], a1[1]};
            } else {
                if (p0 < n)      out[p0]      = (f2){a0[0], a0[1]};
                if (p0 + 32 < n) out[p0 + 32] = (f2){a1[0], a1[1]};
            }
        }
    };

    // ---- depth-2 software pipeline over the grid-stride loop ----
    int c = blockIdx.x;
    f2 xyA = loadx(c);
    f2 xyB = loadx(c + stride < nchunks ? c + stride : c);

    for (; c < nchunks; c += 2 * stride) {
        const int cB  = c + stride;
        const int cA2 = c + 2 * stride;
        const int cB2 = c + 3 * stride;

        f2 xyA2 = loadx(cA2 < nchunks ? cA2 : c);
        f2 xyB2 = loadx(cB2 < nchunks ? cB2 : c);

        body(c, xyA);
        if (cB < nchunks) body(cB, xyB);

        xyA = xyA2;
        xyB = xyB2;
    }
}

extern "C" void kernel_launch(void* const* d_in, const int* in_sizes, int n_in,
                              void* d_out, int out_size, void* d_ws, size_t ws_size,
                              hipStream_t stream) {
    const float* x     = (const float*)d_in[0];
    const float* w_in  = (const float*)d_in[1];
    const float* w_mid = (const float*)d_in[2];
    const float* w_out = (const float*)d_in[3];

    int n = in_sizes[0] / 2;          // number of points
    int nchunks = (n + 255) / 256;
    int blocks = nchunks < 2048 ? nchunks : 2048;  // persistent

    denoiser_mfma32<<<blocks, 256, 0, stream>>>(
        (const f2*)x, w_in, w_mid, w_out, (f2*)d_out, n);
}

// Round 17
// 27.656 us; speedup vs baseline: 1.8754x; 1.6123x over previous
//
#include <hip/hip_runtime.h>

// Denoiser MLP (2->16, 5x 16->16, 16->2), fp32 in/out, via v_mfma_f32_16x16x16_f16.
// R17 synthesis. Model (fits R3-R16): VALUBusy(gfx94x formula) ~= trueVALU +
// MFMA busy => no hidden VALU bloat; kernel is latency-bound on the serial
// MFMA->cvt chain at ~2.5 resident waves/SIMD. Residency is capped by the
// 32x32 shape's 16-reg D/C tuples spilling to AGPRs (CSV VGPR 36-56 <<
// live set => unified total ~200+). Fix: 16x16x16 MFMA (D/C = 4 regs, B/A =
// 2 regs) -> ~70-reg honest footprint -> lb(256,5) -> 5 waves/SIMD; 4
// independent 16-pt tiles/wave for ILP; persistent grid; depth-1 prefetch.
//
// Mapping (all pieces HW-proven in R3/R5/R6):
//   per layer D = A*B, A = weights (16x16), B = activations^T (16 feat x 16 pts)
//   A frag: lane l holds A[i=l&15][k=4*(l>>4)+j], j=0..3
//   B frag: lane l holds B[k=4*(l>>4)+j][n=l&15]
//   D frag: lane l holds D[i=4*(l>>4)+r][n=l&15], r=0..3
//   D layout == B layout (row plays k) -> layers chain in-register (R3).
// Input trick (R6's wi0/wi1 generalized to 4): bin = pack2(cvtpk(x,y),0) puts
// lane l's point at k=4*(l>>4)+{0,1}, col l&15. Variant wi_t = W_in at
// k={4t,4t+1} (zero elsewhere, held only by g==t lanes) selects group-t
// lanes' points: tile t = points base+16t..base+16t+15. One cvtpk feeds all
// 4 input MFMAs. Output: wo rows 0,1 -> D regs 0,1 @ group 0 (lanes 0-15).

typedef _Float16 h4v __attribute__((ext_vector_type(4)));
typedef float f4 __attribute__((ext_vector_type(4)));
typedef float f2 __attribute__((ext_vector_type(2)));
typedef unsigned int u32;
typedef u32 u2v __attribute__((ext_vector_type(2)));

static __device__ __forceinline__ f4 mfma16(h4v a, h4v b, f4 c) {
    return __builtin_amdgcn_mfma_f32_16x16x16f16(a, b, c, 0, 0, 0);
}

static __device__ __forceinline__ u32 cvtpk(float a, float b) {
    return __builtin_bit_cast(u32, __builtin_amdgcn_cvt_pkrtz(a, b));
}

static __device__ __forceinline__ h4v pack2(u32 lo, u32 hi) {
    u2v p = {lo, hi};
    return __builtin_bit_cast(h4v, p);
}

// weight A-fragment: rows = lane&15, cols 4g..4g+3
static __device__ __forceinline__ h4v wfrag(const float* row, int g) {
    const f4* r4 = (const f4*)row;
    f4 q = r4[g];
    return pack2(cvtpk(q.x, q.y), cvtpk(q.z, q.w));
}

// relu + cvt of D regs 0-3 -> next layer's B fragment (order-preserving)
static __device__ __forceinline__ h4v cvt_relu4(f4 a) {
    h4v hb = pack2(cvtpk(a[0], a[1]), cvtpk(a[2], a[3]));
    const h4v z = {};
    return __builtin_elementwise_max(hb, z);   // 2x v_pk_max_f16
}

__global__ __launch_bounds__(256, 5) void denoiser_mfma16(
    const f2* __restrict__ x,        // [N] points (x0,x1)
    const float* __restrict__ w_in,  // [16][2]
    const float* __restrict__ w_mid, // [5][16][16]
    const float* __restrict__ w_out, // [2][16]
    f2* __restrict__ out,            // [N] (o0,o1)
    int n)
{
    const int lane = threadIdx.x & 63;
    const int nn   = lane & 15;   // A-row / point-in-tile
    const int g    = lane >> 4;   // k-group (4 k per group)
    const int wave = threadIdx.x >> 6;

    const h4v hz = {};

    // ---- one-time weight fragments ----
    // input variants: wi_t nonzero only for g==t lanes, k-slots j0,j1 = W_in row
    u32 wxy = cvtpk(w_in[2 * nn], w_in[2 * nn + 1]);
    h4v wi0 = g == 0 ? pack2(wxy, 0u) : hz;
    h4v wi1 = g == 1 ? pack2(wxy, 0u) : hz;
    h4v wi2 = g == 2 ? pack2(wxy, 0u) : hz;
    h4v wi3 = g == 3 ? pack2(wxy, 0u) : hz;

    h4v wm0 = wfrag(w_mid + 0 * 256 + nn * 16, g);
    h4v wm1 = wfrag(w_mid + 1 * 256 + nn * 16, g);
    h4v wm2 = wfrag(w_mid + 2 * 256 + nn * 16, g);
    h4v wm3 = wfrag(w_mid + 3 * 256 + nn * 16, g);
    h4v wm4 = wfrag(w_mid + 4 * 256 + nn * 16, g);

    h4v wo = nn < 2 ? wfrag(w_out + nn * 16, g) : hz;

    // one-time pin: zero C-operand (4 regs) resident, un-rematerializable
    f4 z4 = {};
    asm("" : "+v"(z4));

    const int nchunks = (n + 255) >> 8;     // 256-pt block chunks
    const int stride  = gridDim.x;
    const int nm1     = n - 1;

    auto loadx = [&](int c) -> f2 {
        int pi = c * 256 + wave * 64 + lane;
        return x[pi < n ? pi : nm1];
    };

    int c = blockIdx.x;
    f2 xy = loadx(c);

    for (; c < nchunks; c += stride) {
        // depth-1 prefetch of next chunk (issued before the compute chain)
        const int cn = c + stride;
        f2 xyn = loadx(cn < nchunks ? cn : c);

        const int base = c * 256 + wave * 64;

        // ---- input layer: ONE packed bin, 4 group-selecting A variants ----
        h4v bin = pack2(cvtpk(xy.x, xy.y), 0u);
        f4 a0 = mfma16(wi0, bin, z4);   // pts base+ 0..15
        f4 a1 = mfma16(wi1, bin, z4);   // pts base+16..31
        f4 a2 = mfma16(wi2, bin, z4);   // pts base+32..47
        f4 a3 = mfma16(wi3, bin, z4);   // pts base+48..63
        h4v b0 = cvt_relu4(a0);
        h4v b1 = cvt_relu4(a1);
        h4v b2 = cvt_relu4(a2);
        h4v b3 = cvt_relu4(a3);

        // ---- 5 mid layers: 4 independent tiles (ILP) ----
        a0 = mfma16(wm0, b0, z4);  a1 = mfma16(wm0, b1, z4);
        a2 = mfma16(wm0, b2, z4);  a3 = mfma16(wm0, b3, z4);
        b0 = cvt_relu4(a0);  b1 = cvt_relu4(a1);
        b2 = cvt_relu4(a2);  b3 = cvt_relu4(a3);

        a0 = mfma16(wm1, b0, z4);  a1 = mfma16(wm1, b1, z4);
        a2 = mfma16(wm1, b2, z4);  a3 = mfma16(wm1, b3, z4);
        b0 = cvt_relu4(a0);  b1 = cvt_relu4(a1);
        b2 = cvt_relu4(a2);  b3 = cvt_relu4(a3);

        a0 = mfma16(wm2, b0, z4);  a1 = mfma16(wm2, b1, z4);
        a2 = mfma16(wm2, b2, z4);  a3 = mfma16(wm2, b3, z4);
        b0 = cvt_relu4(a0);  b1 = cvt_relu4(a1);
        b2 = cvt_relu4(a2);  b3 = cvt_relu4(a3);

        a0 = mfma16(wm3, b0, z4);  a1 = mfma16(wm3, b1, z4);
        a2 = mfma16(wm3, b2, z4);  a3 = mfma16(wm3, b3, z4);
        b0 = cvt_relu4(a0);  b1 = cvt_relu4(a1);
        b2 = cvt_relu4(a2);  b3 = cvt_relu4(a3);

        a0 = mfma16(wm4, b0, z4);  a1 = mfma16(wm4, b1, z4);
        a2 = mfma16(wm4, b2, z4);  a3 = mfma16(wm4, b3, z4);
        b0 = cvt_relu4(a0);  b1 = cvt_relu4(a1);
        b2 = cvt_relu4(a2);  b3 = cvt_relu4(a3);

        // ---- output layer: rows 0,1 -> regs 0,1 @ group 0 ----
        a0 = mfma16(wo, b0, z4);
        a1 = mfma16(wo, b1, z4);
        a2 = mfma16(wo, b2, z4);
        a3 = mfma16(wo, b3, z4);

        if (lane < 16) {
            int p0 = base + nn;
            if (base + 64 <= n) {
                out[p0]      = (f2){a0[0], a0[1]};
                out[p0 + 16] = (f2){a1[0], a1[1]};
                out[p0 + 32] = (f2){a2[0], a2[1]};
                out[p0 + 48] = (f2){a3[0], a3[1]};
            } else {
                if (p0 < n)      out[p0]      = (f2){a0[0], a0[1]};
                if (p0 + 16 < n) out[p0 + 16] = (f2){a1[0], a1[1]};
                if (p0 + 32 < n) out[p0 + 32] = (f2){a2[0], a2[1]};
                if (p0 + 48 < n) out[p0 + 48] = (f2){a3[0], a3[1]};
            }
        }

        xy = xyn;
    }
}

extern "C" void kernel_launch(void* const* d_in, const int* in_sizes, int n_in,
                              void* d_out, int out_size, void* d_ws, size_t ws_size,
                              hipStream_t stream) {
    const float* x     = (const float*)d_in[0];
    const float* w_in  = (const float*)d_in[1];
    const float* w_mid = (const float*)d_in[2];
    const float* w_out = (const float*)d_in[3];

    int n = in_sizes[0] / 2;          // number of points
    int nchunks = (n + 255) / 256;
    int blocks = nchunks < 2048 ? nchunks : 2048;  // persistent

    denoiser_mfma16<<<blocks, 256, 0, stream>>>(
        (const f2*)x, w_in, w_mid, w_out, (f2*)d_out, n);
}